// Round 18
// baseline (48.605 us; speedup 1.0000x reference)
//
#include <hip/hip_runtime.h>
#include <math.h>

#define THREADS 256
#define CROP_GRID 1024
#define NTASK (56 * 3 * 28)

typedef float f32x4 __attribute__((ext_vector_type(4)));

// ---------------- Launch 1: chansum (8*K blocks) + logits1 (8*LK blocks) --
template <int LK>
__global__ __launch_bounds__(THREADS) void fused1_kernel(const float* __restrict__ fm,
                                                         float4* __restrict__ part,
                                                         int cpc, int K,
                                                         const float* __restrict__ emb,
                                                         const float* __restrict__ W,
                                                         float* __restrict__ lpart) {
    constexpr int LROWS = 2048 / LK;
    int blk = blockIdx.x;
    int t = threadIdx.x;
    if (blk < 8 * K) {
        int b = blk / K, k = blk - b * K;
        if (t >= 196) return;
        const float4* f = (const float4*)(fm + ((size_t)b * 384 + (size_t)k * cpc) * 784);
        float4 acc = {0.0f, 0.0f, 0.0f, 0.0f};
        for (int c = 0; c < cpc; ++c) {
            float4 v = f[(size_t)c * 196 + t];
            acc.x += v.x; acc.y += v.y; acc.z += v.z; acc.w += v.w;
        }
        part[((size_t)b * K + k) * 196 + t] = acc;
    } else {
        int idx = blk - 8 * K;
        int b = idx / LK, kc = idx - b * LK;
        if (t >= 200) return;
        const float* e  = emb + (size_t)b * 2048 + kc * LROWS;
        const float* wp = W + (size_t)kc * LROWS * 200 + t;
        float a0 = 0.0f, a1 = 0.0f, a2 = 0.0f, a3 = 0.0f;
        #pragma unroll
        for (int k = 0; k < LROWS; k += 4) {
            a0 += e[k]     * wp[(size_t)k * 200];
            a1 += e[k + 1] * wp[(size_t)(k + 1) * 200];
            a2 += e[k + 2] * wp[(size_t)(k + 2) * 200];
            a3 += e[k + 3] * wp[(size_t)(k + 3) * 200];
        }
        lpart[((size_t)b * LK + kc) * 200 + t] = (a0 + a1) + (a2 + a3);
    }
}

// ---------------- Launch 2: score+NMS (24 blocks) + logits2 (8 blocks) ----
// NMS selection runs on ONE wave, scores in registers: no barriers, no LDS
// round-trips in the greedy loop. Tie-break preserved: ascending lane-local
// scan keeps first occurrence; butterfly combines (max value, min index).
template <int LK>
__global__ __launch_bounds__(THREADS) void fused2_kernel(const float4* __restrict__ part,
                                                         int K,
                                                         float* __restrict__ all_scores,
                                                         float* __restrict__ out_idx_f,
                                                         float* __restrict__ out_sc,
                                                         int* __restrict__ ws_idx,
                                                         int* __restrict__ soff,
                                                         const int* __restrict__ coords,
                                                         const float* __restrict__ lpart,
                                                         const float* __restrict__ bias,
                                                         float* __restrict__ logits) {
    __shared__ float4 s4[196];
    __shared__ float  pref[28][29];
    __shared__ float  scl[625];
    int t = threadIdx.x;

    if (blockIdx.x >= 24) {          // logits2: reduce partials + bias, 1 block/batch
        int b = blockIdx.x - 24;
        if (t >= 200) return;
        float a0 = bias[t], a1 = 0.0f, a2 = 0.0f, a3 = 0.0f;
        const float* lp = lpart + (size_t)b * LK * 200 + t;
        #pragma unroll
        for (int kc = 0; kc < LK; kc += 4) {
            a0 += lp[(size_t)kc * 200];
            a1 += lp[(size_t)(kc + 1) * 200];
            a2 += lp[(size_t)(kc + 2) * 200];
            a3 += lp[(size_t)(kc + 3) * 200];
        }
        logits[b * 200 + t] = (a0 + a1) + (a2 + a3);
        return;
    }

    int b = blockIdx.x / 3, g = blockIdx.x - b * 3;

    if (t < 196) {
        float4 acc = {0.0f, 0.0f, 0.0f, 0.0f};
        #pragma unroll 16
        for (int k = 0; k < K; ++k) {
            float4 v = part[((size_t)b * K + k) * 196 + t];
            acc.x += v.x; acc.y += v.y; acc.z += v.z; acc.w += v.w;
        }
        s4[t] = acc;
    }
    __syncthreads();
    if (t < 28) {
        float4 row[7];
        #pragma unroll
        for (int i = 0; i < 7; ++i) row[i] = s4[t * 7 + i];
        float run = 0.0f;
        pref[t][0] = 0.0f;
        #pragma unroll
        for (int j = 0; j < 28; ++j) {
            run += ((float*)row)[j];
            pref[t][j + 1] = run;
        }
    }
    __syncthreads();

    const int gnA[3]   = {625, 529, 441};
    const int sideA[3] = {25, 23, 21};
    const int rA[3]    = {4, 6, 8};
    const int nselA[3] = {2, 3, 2};
    const int colA[3]  = {0, 2, 5};
    const int goffA[3] = {0, 625, 1154};

    int n = gnA[g], side = sideA[g], r = rA[g];
    int nsel = nselA[g], goff = goffA[g], colbase = colA[g];
    float inv = 1.0f / (float)(r * r);

    for (int loc = t; loc < n; loc += THREADS) {
        int i = loc / side, j = loc % side;
        float acc = 0.0f;
        for (int a = 0; a < r; ++a)
            acc += pref[i + a][j + r] - pref[i + a][j];
        float sv = acc * inv;
        scl[loc] = sv;
        all_scores[b * 1595 + goff + loc] = sv;
    }
    __syncthreads();

    if (t >= 64) return;             // ---- single-wave greedy NMS ----

    int PER = (n + 63) / 64;         // 10 / 9 / 7
    int base = t * PER;
    float val[10];
    #pragma unroll
    for (int q = 0; q < 10; ++q)
        val[q] = (q < PER && base + q < n) ? scl[base + q] : -INFINITY;

    float ext = (float)(r * 16 + 1);
    float A   = ext * ext;
    float rs  = (float)(r * 16);

    for (int k = 0; k < nsel; ++k) {
        float bv = -INFINITY; int bi = 0x7fffffff;
        #pragma unroll
        for (int q = 0; q < 10; ++q) {
            if (q < PER && val[q] > bv) { bv = val[q]; bi = base + q; }
        }
        #pragma unroll
        for (int m = 1; m < 64; m <<= 1) {
            float ov = __shfl_xor(bv, m, 64);
            int   oi = __shfl_xor(bi, m, 64);
            if (ov > bv || (ov == bv && oi < bi)) { bv = ov; bi = oi; }
        }
        if (t == 0) {
            int outp = b * 7 + colbase + k;
            int gi   = goff + bi;
            out_idx_f[outp] = (float)gi;
            out_sc[outp]    = bv;
            ws_idx[outp]    = gi;
            soff[outp]      = coords[gi * 4 + 0] * 448 + coords[gi * 4 + 1];
        }
        int si = bi / side, sj = bi % side;
        float sx0 = si * 16.0f, sy0 = sj * 16.0f;
        float sx1 = sx0 + rs,   sy1 = sy0 + rs;
        #pragma unroll
        for (int q = 0; q < 10; ++q) {
            if (q >= PER) continue;
            int idx = base + q;
            if (idx >= n) continue;
            int ii = idx / side, jj = idx % side;
            float x0 = ii * 16.0f, y0 = jj * 16.0f;
            float x1 = x0 + rs,    y1 = y0 + rs;
            float xx0 = fmaxf(x0, sx0), yy0 = fmaxf(y0, sy0);
            float xx1 = fminf(x1, sx1), yy1 = fminf(y1, sy1);
            float w = xx1 - xx0 + 1.0f, h = yy1 - yy0 + 1.0f;
            float inter = (w < 0.0f || h < 0.0f) ? 0.0f : w * h;
            float iou = inter / (A + A - inter);
            if (iou > 0.25f) val[q] = -INFINITY;
        }
    }
}

// ---------------- Launch 3: persistent pipelined crop (R15 verbatim) ------
__global__ __launch_bounds__(448) void crop_kernel(const float* __restrict__ x,
                                                   const int* __restrict__ soff,
                                                   float* __restrict__ out) {
    __shared__ float lds[2][924];
    int t = threadIdx.x;

    int rr0 = t / 132, xx0 = t - rr0 * 132;          // staged idx t
    int i1  = t + 448;
    int rr1 = i1 / 132, xx1 = i1 - rr1 * 132;        // staged idx t+448
    int xx2 = t + 104;                               // staged idx t+896 (rr=6, t<28)
    int row_sub = t / 56;                            // 0..7
    int seg     = t - row_sub * 56;                  // 0..55
    int ox0 = seg * 8;

    int task = blockIdx.x;
    int cw; float cscale, cwm1; int cS, crlo; float* coutb;
    float rA, rB, rC = 0.0f;
    {
        int p = task / 84, rem = task - p * 84;
        int ch = rem / 28, stripe = rem - ch * 28;
        int b = p / 7, col = p - b * 7;
        int g = (col < 2) ? 0 : ((col < 5) ? 1 : 2);
        cw = (g == 0) ? 64 : ((g == 1) ? 96 : 128);
        cscale = (float)cw * (1.0f / 448.0f);
        cwm1 = (float)(cw - 1);
        cS = stripe * 16;
        float syb = fminf(fmaxf(((float)cS + 0.5f) * cscale - 0.5f, 0.0f), cwm1);
        crlo = (int)syb;
        const float* cbase = x + ((size_t)(b * 3 + ch)) * 200704 + soff[p];
        coutb = out + ((size_t)(p * 3 + ch)) * 200704;
        rA = cbase[(size_t)min(crlo + rr0, cw - 1) * 448 + min(xx0, cw - 1)];
        rB = cbase[(size_t)min(crlo + rr1, cw - 1) * 448 + min(xx1, cw - 1)];
        if (t < 28)
            rC = cbase[(size_t)min(crlo + 6, cw - 1) * 448 + min(xx2, cw - 1)];
    }

    int buf = 0;
    while (true) {
        int nxt = task + CROP_GRID;
        bool has = nxt < NTASK;

        lds[buf][t]       = rA;
        lds[buf][t + 448] = rB;
        if (t < 28) lds[buf][t + 896] = rC;

        int nw = 0, nrlo = 0, nS = 0;
        float nscale = 0.0f, nwm1 = 0.0f;
        float* noutb = nullptr;
        if (has) {
            int p = nxt / 84, rem = nxt - p * 84;
            int ch = rem / 28, stripe = rem - ch * 28;
            int b = p / 7, col = p - b * 7;
            int g = (col < 2) ? 0 : ((col < 5) ? 1 : 2);
            nw = (g == 0) ? 64 : ((g == 1) ? 96 : 128);
            nscale = (float)nw * (1.0f / 448.0f);
            nwm1 = (float)(nw - 1);
            nS = stripe * 16;
            float syb = fminf(fmaxf(((float)nS + 0.5f) * nscale - 0.5f, 0.0f), nwm1);
            nrlo = (int)syb;
            const float* nbase = x + ((size_t)(b * 3 + ch)) * 200704 + soff[p];
            noutb = out + ((size_t)(p * 3 + ch)) * 200704;
            rA = nbase[(size_t)min(nrlo + rr0, nw - 1) * 448 + min(xx0, nw - 1)];
            rB = nbase[(size_t)min(nrlo + rr1, nw - 1) * 448 + min(xx1, nw - 1)];
            if (t < 28)
                rC = nbase[(size_t)min(nrlo + 6, nw - 1) * 448 + min(xx2, nw - 1)];
        }

        __syncthreads();

        {
            float sxb = ((float)ox0 + 0.5f) * cscale - 0.5f;
            float sxc = fminf(fmaxf(sxb, 0.0f), cwm1);
            int   i0  = (int)sxc;
            float txk[8];
            bool  e1[8], e2[8];
            #pragma unroll
            for (int k = 0; k < 8; ++k) {
                float sx = fminf(fmaxf(sxb + (float)k * cscale, 0.0f), cwm1);
                int xi = (int)sx;
                txk[k] = sx - (float)xi;
                int d  = xi - i0;
                e1[k] = (d >= 1);
                e2[k] = (d >= 2);
            }
            const float* lbase = &lds[buf][0];
            #pragma unroll
            for (int half = 0; half < 2; ++half) {
                int oy = cS + half * 8 + row_sub;
                float sy = fminf(fmaxf(((float)oy + 0.5f) * cscale - 0.5f, 0.0f), cwm1);
                int   y0 = (int)sy;
                int   y1 = min(y0 + 1, cw - 1);
                float ty = sy - (float)y0;
                const float* l0 = lbase + (y0 - crlo) * 132 + i0;
                const float* l1 = lbase + (y1 - crlo) * 132 + i0;
                float a0 = l0[0], a1 = l0[1], a2 = l0[2], a3 = l0[3];
                float b0 = l1[0], b1 = l1[1], b2 = l1[2], b3 = l1[3];
                float da0 = a1 - a0, da1 = a2 - a1, da2 = a3 - a2;
                float db0 = b1 - b0, db1 = b2 - b1, db2 = b3 - b2;

                f32x4 res0, res1;
                #pragma unroll
                for (int k = 0; k < 8; ++k) {
                    float av  = e2[k] ? a2  : (e1[k] ? a1  : a0);
                    float dav = e2[k] ? da2 : (e1[k] ? da1 : da0);
                    float bv  = e2[k] ? b2  : (e1[k] ? b1  : b0);
                    float dbv = e2[k] ? db2 : (e1[k] ? db1 : db0);
                    float top = fmaf(txk[k], dav, av);
                    float bot = fmaf(txk[k], dbv, bv);
                    float rr  = top + ty * (bot - top);
                    if (k < 4) res0[k] = rr; else res1[k - 4] = rr;
                }
                float* orow = coutb + (size_t)oy * 448 + ox0;
                *(f32x4*)orow       = res0;
                *(f32x4*)(orow + 4) = res1;
            }
        }

        if (!has) break;
        cw = nw; cscale = nscale; cwm1 = nwm1; cS = nS; crlo = nrlo; coutb = noutb;
        task = nxt;
        buf ^= 1;
    }
}

extern "C" void kernel_launch(void* const* d_in, const int* in_sizes, int n_in,
                              void* d_out, int out_size, void* d_ws, size_t ws_size,
                              hipStream_t stream) {
    const float* x      = (const float*)d_in[0];   // (8,3,448,448)
    const float* fm     = (const float*)d_in[1];   // (8,384,28,28)
    const float* emb    = (const float*)d_in[2];   // (8,2048)
    const float* Wc     = (const float*)d_in[3];   // (2048,200)
    const float* bc     = (const float*)d_in[4];   // (200,)
    const int*   coords = (const int*)d_in[5];     // (1595,4)

    float* out        = (float*)d_out;
    float* out_idx    = out;                  // 56  (indices, stored as float)
    float* out_sc     = out + 56;             // 56
    float* all_scores = out + 112;            // 12760
    float* imgs       = out + 12872;          // 33718272
    float* logits     = out + 33731144;       // 1600

    int K = 32;
    while (K > 1 && ws_size < 1024 + (size_t)8 * K * 784 * 4 + (size_t)8 * 64 * 200 * 4)
        K >>= 1;
    int cpc = 384 / K;

    int*    ws_idx = (int*)d_ws;                                   // 56 ints @ 0
    int*    soff   = (int*)((char*)d_ws + 256);                    // 56 ints @ 256
    float4* part   = (float4*)((char*)d_ws + 1024);                // 8*K*196 float4
    float*  lpart  = (float*)((char*)d_ws + 1024 + (size_t)8 * K * 784 * 4);

    fused1_kernel<64><<<8 * K + 8 * 64, THREADS, 0, stream>>>(fm, part, cpc, K, emb, Wc, lpart);
    fused2_kernel<64><<<32, THREADS, 0, stream>>>(part, K, all_scores, out_idx, out_sc, ws_idx,
                                                  soff, coords, lpart, bc, logits);
    crop_kernel<<<CROP_GRID, 448, 0, stream>>>(x, soff, imgs);
}